// Round 2
// baseline (205.846 us; speedup 1.0000x reference)
//
#include <hip/hip_runtime.h>
#include <hip/hip_cooperative_groups.h>

namespace cg = cooperative_groups;

// CrossAttention on MI355X (gfx950), bf16 MFMA path.
// B=4, Lq=2048, Lkv=512, dim_q=1024, dim_kv=768, H=8, hd=128.
// R13: (a) gemm_body -> BK=32 double-buffered minimum-2-phase (stage t+1
//      before compute t, ONE __syncthreads per step) hiding global->LDS
//      latency; pair-row [64][64] T2 layout keeps source-swizzle legal for
//      global_load_lds and fragment reads 2-way-free. (b) P4 O-projection
//      split-K across all 1024 blocks (partner writes fp32 partial + flag,
//      main adds; same-XCD pairing bid/bid+512). (c) s_setprio around attn
//      MFMA clusters (m191). Evidence: R12 counters = all-util ~5%,
//      occupancy 47% -> stall-bound on barrier drains + idle blocks.

typedef unsigned short u16;
typedef unsigned int u32;
using short8  = __attribute__((ext_vector_type(8))) short;   // 8 x bf16 (4 VGPRs)
using floatx4 = __attribute__((ext_vector_type(4))) float;

__device__ inline u16 f2bf(float x) {
  union { float f; u32 u; } v; v.f = x;
  u32 r = (v.u + 0x7fffu + ((v.u >> 16) & 1u)) >> 16;  // RNE
  return (u16)r;
}

__device__ inline float fast_exp2(float x) {
#if __has_builtin(__builtin_amdgcn_exp2f)
  return __builtin_amdgcn_exp2f(x);   // v_exp_f32 (natively exp2)
#else
  return exp2f(x);
#endif
}

#define MFMA(a, b, c) __builtin_amdgcn_mfma_f32_16x16x32_bf16(a, b, c, 0, 0, 0)

__device__ inline void async_lds16(const void* g, void* l) {
  __builtin_amdgcn_global_load_lds(
      (const __attribute__((address_space(1))) void*)g,
      (__attribute__((address_space(3))) void*)l, 16, 0, 0);
}

// ------------- fp32 -> bf16 cast body (grid-strided over 1024x256) -------------
__device__ __forceinline__
void cvt_body(const float* __restrict__ q, const float* __restrict__ kv,
              u16* __restrict__ q_bf, u16* __restrict__ kv_bf, int lin) {
  for (int i = lin * 256 + (int)threadIdx.x; i < 1245184; i += 262144) {
    const float* src; u16* dst; int idx;
    if (i < 1048576) { src = q;  dst = q_bf;  idx = i; }
    else             { src = kv; dst = kv_bf; idx = i - 1048576; }
    float4 a = ((const float4*)src)[2 * idx];
    float4 b = ((const float4*)src)[2 * idx + 1];
    u16 t[8] = {f2bf(a.x), f2bf(a.y), f2bf(a.z), f2bf(a.w),
                f2bf(b.x), f2bf(b.y), f2bf(b.z), f2bf(b.w)};
    ((short8*)dst)[idx] = *(short8*)t;
  }
}

// ------------- W [K][N] fp32 -> Wt [N][K] bf16, one 64x64 tile per block -------
__device__ __forceinline__
void transpose_body(int bid, const float* __restrict__ Wq, const float* __restrict__ Wk,
                    const float* __restrict__ Wv, const float* __restrict__ Wo,
                    u16* __restrict__ WqT, u16* __restrict__ WkvT, u16* __restrict__ WoT,
                    float* __restrict__ tile /* [64][68] floats */) {
  const int z = bid >> 8;
  const float* W; u16* Wt; int K;
  if      (z == 0) { W = Wq; Wt = WqT;               K = 1024; }
  else if (z == 1) { W = Wk; Wt = WkvT;              K = 768;  }
  else if (z == 2) { W = Wv; Wt = WkvT + 1024 * 768; K = 768;  }
  else             { W = Wo; Wt = WoT;               K = 1024; }
  const int k0 = ((bid >> 4) & 15) * 64, n0 = (bid & 15) * 64;
  if (k0 >= K) return;  // block-uniform guard
  const int N = 1024;
  const int t = threadIdx.x;
  for (int p = 0; p < 4; ++p) {
    int cid = p * 256 + t;
    int row = cid >> 4, c = cid & 15;
    float4 v = *(const float4*)&W[(long)(k0 + row) * N + n0 + c * 4];
    tile[row * 68 + c * 4 + 0] = v.x; tile[row * 68 + c * 4 + 1] = v.y;
    tile[row * 68 + c * 4 + 2] = v.z; tile[row * 68 + c * 4 + 3] = v.w;
  }
  __syncthreads();
  for (int p = 0; p < 2; ++p) {
    int oc = p * 256 + t;
    int n = oc >> 3, c = oc & 7;
    u16 tmp[8];
    for (int s = 0; s < 8; ++s) tmp[s] = f2bf(tile[(c * 8 + s) * 68 + n]);
    *(short8*)&Wt[(long)(n0 + n) * K + k0 + c * 8] = *(short8*)tmp;
  }
}

// ---------------- bf16 GEMM body: BK=32 double-buffered 2-phase ----------------
// role: 0 = normal epilogue; 1 = split-K partner (write fp32 partial + flag);
//       2 = split-K main (wait flag, acc += partial, then normal epilogue).
__device__ __forceinline__
void gemm_body(const u16* __restrict__ A, const u16* __restrict__ Bt,
               u16* __restrict__ Cb, float* __restrict__ Cf,
               const float* __restrict__ bias, u16* __restrict__ vt_out,
               int K, int ldc, int lin, int mt_per_xcd, u16* smem,
               int k_begin, int k_end, float* __restrict__ partial,
               int* flag, int role) {
  const int tid  = threadIdx.x;
  const int wave = tid >> 6, lane = tid & 63;
  const int l15  = lane & 15, quad = lane >> 4;
  const int wm   = (wave >> 1) * 64, wn = (wave & 1) * 64;
  const int xcd  = lin & 7, slot = lin >> 3;
  const int mt   = xcd * mt_per_xcd + (slot % mt_per_xcd);
  const int nti  = slot / mt_per_xcd;
  const long m0  = (long)mt * 128, n0 = (long)nti * 128;

  // T2 pair-row layout: LDS tile = [64 pair-rows][64 u16]; pair-row p packs
  // rows {2p,2p+1} (32 k each). Logical granule g(0..7) = (r&1)*4 + k/8,
  // stored at position g ^ (p&7). LDS dest of global_load_lds is linear;
  // the involution is applied to the SOURCE address (rule #21).
  const int pl  = lane >> 3;              // pair-row within inst chunk
  const int gg  = (lane & 7) ^ pl;        // logical granule for this lane
  const int ro  = pl * 2 + (gg >> 2);     // source row offset within 16 rows
  const int co  = (gg & 3) * 8;           // source k offset
  const u16* Aw = A  + (m0 + wave * 32 + ro) * (long)K + co;
  const u16* Bw = Bt + (n0 + wave * 32 + ro) * (long)K + co;
  u16* const A0 = smem;        u16* const B0 = smem + 4096;
  u16* const A1 = smem + 8192; u16* const B1 = smem + 12288;
  // Fragment read offsets (u16 units). pos = ((r&1)*4+quad) ^ (p&7) with
  // p&7 = l15>>1 -> 16-lane groups hit every granule exactly twice (2-way free).
  const int rdo  = ((((l15 & 1) << 2) | quad) ^ (l15 >> 1)) * 8;
  const int aoff = wm * 32 + (l15 >> 1) * 64 + rdo;   // (wm/2)*64
  const int boff = wn * 32 + (l15 >> 1) * 64 + rdo;

#define STAGE_G(Ab, Bb, kk)                                        \
  { async_lds16(Aw + (kk),                (Ab) + wave * 1024);       \
    async_lds16(Aw + 16 * (long)K + (kk), (Ab) + wave * 1024 + 512); \
    async_lds16(Bw + (kk),                (Bb) + wave * 1024);       \
    async_lds16(Bw + 16 * (long)K + (kk), (Bb) + wave * 1024 + 512); }

  floatx4 acc[4][4] = {};
  STAGE_G(A0, B0, k_begin);
  const int NS = (k_end - k_begin) >> 5;
  for (int s = 0; s < NS; ++s) {
    __syncthreads();                       // buf[s&1] landed; prev reads done
    u16* Ac = (s & 1) ? A1 : A0; u16* Bc = (s & 1) ? B1 : B0;
    if (s + 1 < NS) {                      // prefetch next step, other buffer
      u16* An = (s & 1) ? A0 : A1; u16* Bn = (s & 1) ? B0 : B1;
      STAGE_G(An, Bn, k_begin + (s + 1) * 32);
    }
    short8 af[4], bfr[4];
    for (int i = 0; i < 4; ++i) af[i]  = *(const short8*)&Ac[aoff + i * 512];
    for (int j = 0; j < 4; ++j) bfr[j] = *(const short8*)&Bc[boff + j * 512];
    for (int i = 0; i < 4; ++i)
      for (int j = 0; j < 4; ++j)
        acc[i][j] = MFMA(af[i], bfr[j], acc[i][j]);
  }
  __syncthreads();
#undef STAGE_G

  if (role == 1) {  // split-K partner: publish partial, raise flag
    for (int i = 0; i < 4; ++i)
      for (int j = 0; j < 4; ++j)
        for (int r = 0; r < 4; ++r)
          __hip_atomic_store(
              &partial[(wm + i * 16 + quad * 4 + r) * 128 + wn + j * 16 + l15],
              acc[i][j][r], __ATOMIC_RELAXED, __HIP_MEMORY_SCOPE_AGENT);
    __threadfence();
    __syncthreads();
    if (tid == 0)
      __hip_atomic_store(flag, 1, __ATOMIC_RELEASE, __HIP_MEMORY_SCOPE_AGENT);
    return;
  }
  if (role == 2) {  // split-K main: consume partner's partial
    if (tid == 0)
      while (__hip_atomic_load(flag, __ATOMIC_ACQUIRE,
                               __HIP_MEMORY_SCOPE_AGENT) == 0)
        __builtin_amdgcn_s_sleep(2);
    __syncthreads();
    __threadfence();
    for (int i = 0; i < 4; ++i)
      for (int j = 0; j < 4; ++j)
        for (int r = 0; r < 4; ++r)
          acc[i][j][r] += __hip_atomic_load(
              &partial[(wm + i * 16 + quad * 4 + r) * 128 + wn + j * 16 + l15],
              __ATOMIC_RELAXED, __HIP_MEMORY_SCOPE_AGENT);
  }

  if (Cf) {
    for (int i = 0; i < 4; ++i)
      for (int j = 0; j < 4; ++j) {
        long row = m0 + wm + i * 16 + quad * 4;
        long col = n0 + wn + j * 16 + l15;
        float b = bias ? bias[col] : 0.f;
        for (int r = 0; r < 4; ++r) Cf[(row + r) * (long)ldc + col] = acc[i][j][r] + b;
      }
    return;
  }
  for (int i = 0; i < 4; ++i)
    for (int j = 0; j < 4; ++j)
      for (int r = 0; r < 4; ++r)
        smem[(wm + i * 16 + quad * 4 + r) * 138 + wn + j * 16 + l15] = f2bf(acc[i][j][r]);
  __syncthreads();
  if (vt_out && nti >= 8) {
    const int h  = nti - 8;
    const int bq = (int)(m0 >> 9);
    const int l0 = (int)(m0 & 511);
    u16* vbase = vt_out + ((long)(bq * 8 + h) * 128) * 512;
    for (int p = 0; p < 8; ++p) {
      int cid = p * 256 + tid;
      int d = cid >> 4, c = cid & 15;
      u16 tmp[8];
      for (int s = 0; s < 8; ++s) tmp[s] = smem[(c * 8 + s) * 138 + d];
      *(short8*)&vbase[(long)d * 512 + l0 + c * 8] = *(short8*)tmp;
    }
  } else {
    for (int p = 0; p < 8; ++p) {
      int cid = p * 256 + tid;
      int row = cid >> 4, c = cid & 15;
      short8 v = *(const short8*)&smem[row * 138 + c * 8];
      *(short8*)&Cb[(m0 + row) * (long)ldc + n0 + c * 8] = v;
    }
  }
}

// ---------------- flash attention body (R6-proven logic + setprio) ----------------
__device__ __forceinline__
void attn_body(const u16* __restrict__ qp, const u16* __restrict__ kp,
               const u16* __restrict__ vT, u16* __restrict__ ctx,
               int lin, u16* smem) {
  u16* Ks = smem;            // [64 k][128 d], granule g at g^(k&15)
  u16* Vs = smem + 8192;     // [128 d][64 k], granule g at g^(d&7)
  const int tid  = threadIdx.x;
  const int wave = tid >> 6, lane = tid & 63;
  u16* Pw = smem + 16384 + wave * 1024;  // per-wave P [16 r][64 k], g^(row&7)
  const int l15  = lane & 15, quad = lane >> 4;
  const int xcd  = lin & 7, slot = lin >> 3;           // slot 0..127
  const int pairIdx = xcd * 4 + (slot & 3);            // 0..31 (b,h)
  const int b = pairIdx >> 3, h = pairIdx & 7;
  const int qtile = slot >> 2;                         // 0..31
  const long rowbase = (long)b * 2048 + qtile * 64 + wave * 16;
  const float sc = 0.08838834764831845f * 1.4426950408889634f;  // scale*log2(e)

  short8 aQ[4];
  for (int dc = 0; dc < 4; ++dc)
    aQ[dc] = *(const short8*)&qp[(rowbase + l15) * 1024 + h * 128 + dc * 32 + quad * 8];

  floatx4 O[8] = {};
  float lsum[4] = {};
  const u16* kpb   = kp + ((long)b * 512) * 1024 + h * 128;
  const u16* vbase = vT + ((long)(b * 8 + h) * 128) * 512;

  const int krow = lane >> 4;
  const int kpos = lane & 15;
  const int vrow = lane >> 3;
  const int vpos = lane & 7;

  for (int t = 0; t < 8; ++t) {
    for (int i = 0; i < 4; ++i) {
      int inst = wave * 4 + i;
      int row  = inst * 4 + krow;
      int g    = kpos ^ (row & 15);
      async_lds16(kpb + (long)(t * 64 + row) * 1024 + g * 8, &Ks[inst * 512]);
    }
    for (int i = 0; i < 4; ++i) {
      int inst = wave * 4 + i;
      int d    = inst * 8 + vrow;
      int g    = vpos ^ (d & 7);
      async_lds16(vbase + (long)d * 512 + t * 64 + g * 8, &Vs[inst * 512]);
    }
    __syncthreads();

    floatx4 S[4] = {};
    __builtin_amdgcn_s_setprio(1);
    for (int dc = 0; dc < 4; ++dc)
      for (int ks = 0; ks < 4; ++ks) {
        int k = ks * 16 + l15;
        short8 bk = *(const short8*)&Ks[k * 128 + (((dc * 4 + quad) ^ l15) * 8)];
        S[ks] = MFMA(aQ[dc], bk, S[ks]);
      }
    __builtin_amdgcn_s_setprio(0);
    for (int ks = 0; ks < 4; ++ks)
      for (int r = 0; r < 4; ++r) {
        float p = fast_exp2(S[ks][r] * sc);
        lsum[r] += p;
        int row = quad * 4 + r;
        int g   = (ks * 2 + (l15 >> 3)) ^ (row & 7);
        Pw[row * 64 + g * 8 + (l15 & 7)] = f2bf(p);
      }
    short8 aP[2];
    for (int kc = 0; kc < 2; ++kc)
      aP[kc] = *(const short8*)&Pw[l15 * 64 + (((kc * 4 + quad) ^ (l15 & 7)) * 8)];
    __builtin_amdgcn_s_setprio(1);
    for (int j = 0; j < 8; ++j) {
      int d = j * 16 + l15;
      short8 bV0 = *(const short8*)&Vs[d * 64 + ((quad ^ (l15 & 7)) * 8)];
      short8 bV1 = *(const short8*)&Vs[d * 64 + (((4 + quad) ^ (l15 & 7)) * 8)];
      O[j] = MFMA(aP[0], bV0, O[j]);
      O[j] = MFMA(aP[1], bV1, O[j]);
    }
    __builtin_amdgcn_s_setprio(0);
    __syncthreads();
  }

  for (int r = 0; r < 4; ++r) {
    float sum = lsum[r];
    for (int off = 1; off < 16; off <<= 1) sum += __shfl_xor(sum, off);
    lsum[r] = 1.f / sum;
  }
  for (int j = 0; j < 8; ++j)
    for (int r = 0; r < 4; ++r)
      ctx[(rowbase + quad * 4 + r) * 1024 + h * 128 + j * 16 + l15] =
          f2bf(O[j][r] * lsum[r]);
}

// ---------------- cooperative mega-kernel ----------------
// grid 1024 x 256, LDS 40960 B, 4 blocks/CU (all co-resident).
__global__ __launch_bounds__(256, 4)
void mega(const float* q, const float* kv, const float* Wq, const float* Wk,
          const float* Wv, const float* Wo,
          u16* q_bf, u16* kv_bf, u16* WqT, u16* WkvT, u16* WoT,
          u16* qp, u16* kp, u16* vT, u16* ctx, float* out, const float* bo,
          int* flags) {
  __shared__ __align__(16) u16 smem[20480];   // 40960 B
  cg::grid_group g = cg::this_grid();
  const int bid = blockIdx.x;

  // P0: casts + weight transposes + split-K flag reset
  cvt_body(q, kv, q_bf, kv_bf, bid);
  transpose_body(bid, Wq, Wk, Wv, Wo, WqT, WkvT, WoT, (float*)smem);
  if (bid == 0 && threadIdx.x < 512) flags[threadIdx.x] = 0;
  g.sync();

  // P2: Q-projection (bid 0..511) + fused KV-projection (bid 512..767)
  if (bid < 768) {
    const bool isQ = bid < 512;
    gemm_body(isQ ? q_bf : kv_bf, isQ ? WqT : WkvT, isQ ? qp : kp,
              nullptr, nullptr, isQ ? (u16*)nullptr : vT,
              isQ ? 1024 : 768, 1024, isQ ? bid : bid - 512, isQ ? 8 : 2, smem,
              0, isQ ? 1024 : 768, nullptr, nullptr, 0);
  }
  g.sync();
  // P3: attention, all 1024 blocks
  attn_body(qp, kp, vT, ctx, bid, smem);
  g.sync();
  // P4: O-projection, split-K across all 1024 blocks.
  // main t = bid (<512): K [0,512); partner bid>=512 for tile t=bid-512:
  // K [512,1024) -> fp32 partial in dead qp/q_bf regions, flag in ws hole.
  {
    const int t = (bid < 512) ? bid : bid - 512;
    float* part = (t < 256) ? ((float*)qp + (long)t * 16384)
                            : ((float*)q_bf + (long)(t - 256) * 16384);
    if (bid < 512)
      gemm_body(ctx, WoT, nullptr, out, bo, nullptr, 1024, 1024, t, 8, smem,
                0, 512, part, flags + t, 2);
    else
      gemm_body(ctx, WoT, nullptr, out, bo, nullptr, 1024, 1024, t, 8, smem,
                512, 1024, part, flags + t, 1);
  }
}

// ---------------- fallback standalone kernels ----------------
__global__ void cvt_all(const float* __restrict__ q, const float* __restrict__ kv,
                        u16* __restrict__ q_bf, u16* __restrict__ kv_bf) {
  int i = blockIdx.x * 256 + threadIdx.x;
  const float* src; u16* dst; int idx;
  if (i < 1048576) { src = q;  dst = q_bf;  idx = i; }
  else             { src = kv; dst = kv_bf; idx = i - 1048576; }
  float4 a = ((const float4*)src)[2 * idx];
  float4 b = ((const float4*)src)[2 * idx + 1];
  u16 t[8] = {f2bf(a.x), f2bf(a.y), f2bf(a.z), f2bf(a.w),
              f2bf(b.x), f2bf(b.y), f2bf(b.z), f2bf(b.w)};
  ((short8*)dst)[idx] = *(short8*)t;
}
__global__ __launch_bounds__(256)
void transpose_all(const float* __restrict__ Wq, const float* __restrict__ Wk,
                   const float* __restrict__ Wv, const float* __restrict__ Wo,
                   u16* __restrict__ WqT, u16* __restrict__ WkvT, u16* __restrict__ WoT) {
  __shared__ __align__(16) float tile[64 * 68];
  int bid = blockIdx.x + blockIdx.y * 16 + blockIdx.z * 256;
  transpose_body(bid, Wq, Wk, Wv, Wo, WqT, WkvT, WoT, tile);
}
__global__ __launch_bounds__(256)
void k_proj_q(const u16* __restrict__ q_bf, const u16* __restrict__ WqT,
              u16* __restrict__ qp) {
  __shared__ __align__(16) u16 smem[17664];
  gemm_body(q_bf, WqT, qp, nullptr, nullptr, nullptr, 1024, 1024, blockIdx.x, 8,
            smem, 0, 1024, nullptr, nullptr, 0);
}
__global__ __launch_bounds__(256)
void k_proj_kv(const u16* __restrict__ kv_bf, const u16* __restrict__ WkvT,
               u16* __restrict__ kp, u16* __restrict__ vT) {
  __shared__ __align__(16) u16 smem[17664];
  gemm_body(kv_bf, WkvT, kp, nullptr, nullptr, vT, 768, 1024, blockIdx.x, 2,
            smem, 0, 768, nullptr, nullptr, 0);
}
__global__ __launch_bounds__(256, 4)
void k_attn(const u16* __restrict__ qp, const u16* __restrict__ kp,
            const u16* __restrict__ vT, u16* __restrict__ ctx) {
  __shared__ __align__(16) u16 smem[20480];
  attn_body(qp, kp, vT, ctx, blockIdx.x, smem);
}
__global__ __launch_bounds__(256)
void k_oproj(const u16* __restrict__ ctx, const u16* __restrict__ WoT,
             float* __restrict__ out, const float* __restrict__ bo) {
  __shared__ __align__(16) u16 smem[17664];
  gemm_body(ctx, WoT, nullptr, out, bo, nullptr, 1024, 1024, blockIdx.x, 8,
            smem, 0, 1024, nullptr, nullptr, 0);
}

extern "C" void kernel_launch(void* const* d_in, const int* in_sizes, int n_in,
                              void* d_out, int out_size, void* d_ws, size_t ws_size,
                              hipStream_t stream) {
  const float* q  = (const float*)d_in[0];
  const float* kv = (const float*)d_in[1];
  const float* Wq = (const float*)d_in[2];
  const float* Wk = (const float*)d_in[3];
  const float* Wv = (const float*)d_in[4];
  const float* Wo = (const float*)d_in[5];
  const float* bo = (const float*)d_in[6];
  float* out = (float*)d_out;

  char* ws = (char*)d_ws;
  u16* q_bf  = (u16*)(ws + 0);              // 16 MB (P4: split-K partial hi)
  u16* kv_bf = (u16*)(ws + 16777216);       //  3 MB
  u16* WqT   = (u16*)(ws + 19922944);       //  2 MB   [1024][1024]
  u16* WkvT  = (u16*)(ws + 22020096);       //  3 MB   [2048][768]
  u16* WoT   = (u16*)(ws + 25165824);       //  2 MB   [1024][1024]
  u16* qp    = (u16*)(ws + 27262976);       // 16 MB   (P4: split-K partial lo)
  u16* kp    = (u16*)(ws + 44040192);       //  4 MB   [2048][1024]
  int* flags = (int*)(ws + 48234496);       //  2 KB   (hole: kp end .. vT start)
  u16* vT    = (u16*)(ws + 52428800);       //  4 MB   [B][H][128][512]
  u16* ctx   = (u16*)(ws + 56623104);       // 16 MB   [8192][1024]

  // deterministic per-device decision (same every call; pure host query)
  int maxb = 0;
  hipError_t oe = hipOccupancyMaxActiveBlocksPerMultiprocessor(
      &maxb, (const void*)mega, 256, 0);
  if (oe == hipSuccess && maxb >= 4) {
    void* args[] = {(void*)&q,    (void*)&kv,    (void*)&Wq,   (void*)&Wk,
                    (void*)&Wv,   (void*)&Wo,    (void*)&q_bf, (void*)&kv_bf,
                    (void*)&WqT,  (void*)&WkvT,  (void*)&WoT,  (void*)&qp,
                    (void*)&kp,   (void*)&vT,    (void*)&ctx,  (void*)&out,
                    (void*)&bo,   (void*)&flags};
    hipLaunchCooperativeKernel((const void*)mega, dim3(1024), dim3(256),
                               args, 0, stream);
  } else {
    cvt_all<<<4864, 256, 0, stream>>>(q, kv, q_bf, kv_bf);
    transpose_all<<<dim3(16, 16, 4), 256, 0, stream>>>(Wq, Wk, Wv, Wo, WqT, WkvT, WoT);
    k_proj_q<<<512, 256, 0, stream>>>(q_bf, WqT, qp);
    k_proj_kv<<<256, 256, 0, stream>>>(kv_bf, WkvT, kp, vT);
    k_attn<<<1024, 256, 0, stream>>>(qp, kp, vT, ctx);
    k_oproj<<<512, 256, 0, stream>>>(ctx, WoT, out, bo);
  }
}

// Round 3
// 199.110 us; speedup vs baseline: 1.0338x; 1.0338x over previous
//
#include <hip/hip_runtime.h>
#include <hip/hip_cooperative_groups.h>

namespace cg = cooperative_groups;

// CrossAttention on MI355X (gfx950), bf16 MFMA path.
// B=4, Lq=2048, Lkv=512, dim_q=1024, dim_kv=768, H=8, hd=128.
// R14: true T3+T4 (counted vmcnt + raw s_barrier, no __syncthreads drain) in
//      both gemm_body (BK=32 dbuf, stage s+1 in flight across barriers) and
//      attn_body (K(t+1) staged during softmax+PV, V(t+1) during QK+softmax;
//      Ks dead after QK, Vs dead after PV -> no extra LDS). Split-K dropped
//      (R13: +32MB HBM, net negative). R12 T2 swizzles kept (conflicts 1e6).

typedef unsigned short u16;
typedef unsigned int u32;
using short8  = __attribute__((ext_vector_type(8))) short;   // 8 x bf16 (4 VGPRs)
using floatx4 = __attribute__((ext_vector_type(4))) float;

__device__ inline u16 f2bf(float x) {
  union { float f; u32 u; } v; v.f = x;
  u32 r = (v.u + 0x7fffu + ((v.u >> 16) & 1u)) >> 16;  // RNE
  return (u16)r;
}

__device__ inline float fast_exp2(float x) {
#if __has_builtin(__builtin_amdgcn_exp2f)
  return __builtin_amdgcn_exp2f(x);   // v_exp_f32 (natively exp2)
#else
  return exp2f(x);
#endif
}

#define MFMA(a, b, c) __builtin_amdgcn_mfma_f32_16x16x32_bf16(a, b, c, 0, 0, 0)

__device__ inline void async_lds16(const void* g, void* l) {
  __builtin_amdgcn_global_load_lds(
      (const __attribute__((address_space(1))) void*)g,
      (__attribute__((address_space(3))) void*)l, 16, 0, 0);
}

// Counted waits + raw barrier (T4). sched_barrier(0) pins ordering (rule #18).
#define WAIT_VM(n) { asm volatile("s_waitcnt vmcnt(" #n ")" ::: "memory"); \
                     __builtin_amdgcn_sched_barrier(0); }
#define WAIT_LGKM0 { asm volatile("s_waitcnt lgkmcnt(0)" ::: "memory"); \
                     __builtin_amdgcn_sched_barrier(0); }
#define SBAR       { __builtin_amdgcn_s_barrier(); \
                     __builtin_amdgcn_sched_barrier(0); }

// ------------- fp32 -> bf16 cast body (grid-strided over 1024x256) -------------
__device__ __forceinline__
void cvt_body(const float* __restrict__ q, const float* __restrict__ kv,
              u16* __restrict__ q_bf, u16* __restrict__ kv_bf, int lin) {
  for (int i = lin * 256 + (int)threadIdx.x; i < 1245184; i += 262144) {
    const float* src; u16* dst; int idx;
    if (i < 1048576) { src = q;  dst = q_bf;  idx = i; }
    else             { src = kv; dst = kv_bf; idx = i - 1048576; }
    float4 a = ((const float4*)src)[2 * idx];
    float4 b = ((const float4*)src)[2 * idx + 1];
    u16 t[8] = {f2bf(a.x), f2bf(a.y), f2bf(a.z), f2bf(a.w),
                f2bf(b.x), f2bf(b.y), f2bf(b.z), f2bf(b.w)};
    ((short8*)dst)[idx] = *(short8*)t;
  }
}

// ------------- W [K][N] fp32 -> Wt [N][K] bf16, one 64x64 tile per block -------
__device__ __forceinline__
void transpose_body(int bid, const float* __restrict__ Wq, const float* __restrict__ Wk,
                    const float* __restrict__ Wv, const float* __restrict__ Wo,
                    u16* __restrict__ WqT, u16* __restrict__ WkvT, u16* __restrict__ WoT,
                    float* __restrict__ tile /* [64][68] floats */) {
  const int z = bid >> 8;
  const float* W; u16* Wt; int K;
  if      (z == 0) { W = Wq; Wt = WqT;               K = 1024; }
  else if (z == 1) { W = Wk; Wt = WkvT;              K = 768;  }
  else if (z == 2) { W = Wv; Wt = WkvT + 1024 * 768; K = 768;  }
  else             { W = Wo; Wt = WoT;               K = 1024; }
  const int k0 = ((bid >> 4) & 15) * 64, n0 = (bid & 15) * 64;
  if (k0 >= K) return;  // block-uniform guard
  const int N = 1024;
  const int t = threadIdx.x;
  for (int p = 0; p < 4; ++p) {
    int cid = p * 256 + t;
    int row = cid >> 4, c = cid & 15;
    float4 v = *(const float4*)&W[(long)(k0 + row) * N + n0 + c * 4];
    tile[row * 68 + c * 4 + 0] = v.x; tile[row * 68 + c * 4 + 1] = v.y;
    tile[row * 68 + c * 4 + 2] = v.z; tile[row * 68 + c * 4 + 3] = v.w;
  }
  __syncthreads();
  for (int p = 0; p < 2; ++p) {
    int oc = p * 256 + t;
    int n = oc >> 3, c = oc & 7;
    u16 tmp[8];
    for (int s = 0; s < 8; ++s) tmp[s] = f2bf(tile[(c * 8 + s) * 68 + n]);
    *(short8*)&Wt[(long)(n0 + n) * K + k0 + c * 8] = *(short8*)tmp;
  }
}

// ------- bf16 GEMM body: BK=32 dbuf, counted-vmcnt pipeline (T3+T4) -------
__device__ __forceinline__
void gemm_body(const u16* __restrict__ A, const u16* __restrict__ Bt,
               u16* __restrict__ Cb, float* __restrict__ Cf,
               const float* __restrict__ bias, u16* __restrict__ vt_out,
               int K, int ldc, int lin, int mt_per_xcd, u16* smem) {
  const int tid  = threadIdx.x;
  const int wave = tid >> 6, lane = tid & 63;
  const int l15  = lane & 15, quad = lane >> 4;
  const int wm   = (wave >> 1) * 64, wn = (wave & 1) * 64;
  const int xcd  = lin & 7, slot = lin >> 3;
  const int mt   = xcd * mt_per_xcd + (slot % mt_per_xcd);
  const int nti  = slot / mt_per_xcd;
  const long m0  = (long)mt * 128, n0 = (long)nti * 128;

  // T2 pair-row layout (R13-verified): LDS buf = [64 pair-rows][64 u16];
  // pair-row p packs rows {2p,2p+1} x 32 k. Logical granule g = (r&1)*4+k/8
  // stored at g ^ (p&7); involution applied to the SOURCE addr (rule #21).
  const int pl  = lane >> 3;
  const int gg  = (lane & 7) ^ pl;
  const int ro  = pl * 2 + (gg >> 2);
  const int co  = (gg & 3) * 8;
  const u16* Aw = A  + (m0 + wave * 32 + ro) * (long)K + co;
  const u16* Bw = Bt + (n0 + wave * 32 + ro) * (long)K + co;
  u16* const A0 = smem;        u16* const B0 = smem + 4096;
  u16* const A1 = smem + 8192; u16* const B1 = smem + 12288;
  const int rdo  = ((((l15 & 1) << 2) | quad) ^ (l15 >> 1)) * 8;
  const int aoff = wm * 32 + (l15 >> 1) * 64 + rdo;
  const int boff = wn * 32 + (l15 >> 1) * 64 + rdo;

#define STAGE_G(Ab, Bb, kk)                                          \
  { async_lds16(Aw + (kk),                (Ab) + wave * 1024);       \
    async_lds16(Aw + 16 * (long)K + (kk), (Ab) + wave * 1024 + 512); \
    async_lds16(Bw + (kk),                (Bb) + wave * 1024);       \
    async_lds16(Bw + 16 * (long)K + (kk), (Bb) + wave * 1024 + 512); }

  floatx4 acc[4][4] = {};
  STAGE_G(A0, B0, 0);
  const int NS = K >> 5;
  for (int s = 0; s < NS; ++s) {
    u16* Ac = (s & 1) ? A1 : A0; u16* Bc = (s & 1) ? B1 : B0;
    if (s + 1 < NS) {           // issue next stage FIRST; it flies over compute
      u16* An = (s & 1) ? A0 : A1; u16* Bn = (s & 1) ? B0 : B1;
      STAGE_G(An, Bn, (s + 1) * 32);
      WAIT_VM(4);               // stage(s) landed; stage(s+1) stays in flight
    } else {
      WAIT_VM(0);
    }
    SBAR;                       // all waves' stage(s) landed
    short8 af[4], bfr[4];
    for (int i = 0; i < 4; ++i) af[i]  = *(const short8*)&Ac[aoff + i * 512];
    for (int j = 0; j < 4; ++j) bfr[j] = *(const short8*)&Bc[boff + j * 512];
    for (int i = 0; i < 4; ++i)
      for (int j = 0; j < 4; ++j)
        acc[i][j] = MFMA(af[i], bfr[j], acc[i][j]);
    WAIT_LGKM0;                 // this wave's reads of buf[s&1] retired
    SBAR;                       // everyone done -> safe to overwrite next iter
  }
#undef STAGE_G

  if (Cf) {
    for (int i = 0; i < 4; ++i)
      for (int j = 0; j < 4; ++j) {
        long row = m0 + wm + i * 16 + quad * 4;
        long col = n0 + wn + j * 16 + l15;
        float b = bias ? bias[col] : 0.f;
        for (int r = 0; r < 4; ++r) Cf[(row + r) * (long)ldc + col] = acc[i][j][r] + b;
      }
    return;
  }
  for (int i = 0; i < 4; ++i)
    for (int j = 0; j < 4; ++j)
      for (int r = 0; r < 4; ++r)
        smem[(wm + i * 16 + quad * 4 + r) * 138 + wn + j * 16 + l15] = f2bf(acc[i][j][r]);
  __syncthreads();
  if (vt_out && nti >= 8) {
    const int h  = nti - 8;
    const int bq = (int)(m0 >> 9);
    const int l0 = (int)(m0 & 511);
    u16* vbase = vt_out + ((long)(bq * 8 + h) * 128) * 512;
    for (int p = 0; p < 8; ++p) {
      int cid = p * 256 + tid;
      int d = cid >> 4, c = cid & 15;
      u16 tmp[8];
      for (int s = 0; s < 8; ++s) tmp[s] = smem[(c * 8 + s) * 138 + d];
      *(short8*)&vbase[(long)d * 512 + l0 + c * 8] = *(short8*)tmp;
    }
  } else {
    for (int p = 0; p < 8; ++p) {
      int cid = p * 256 + tid;
      int row = cid >> 4, c = cid & 15;
      short8 v = *(const short8*)&smem[row * 138 + c * 8];
      *(short8*)&Cb[(m0 + row) * (long)ldc + n0 + c * 8] = v;
    }
  }
}

// ------- flash attention body: counted-vmcnt K/V cross-staging (T3+T4) -------
// Ks is dead after QK^T, Vs dead after PV: stage K(t+1) during softmax+PV,
// stage V(t+1) during QK(t+1)+softmax. No layout change vs R12.
__device__ __forceinline__
void attn_body(const u16* __restrict__ qp, const u16* __restrict__ kp,
               const u16* __restrict__ vT, u16* __restrict__ ctx,
               int lin, u16* smem) {
  u16* Ks = smem;            // [64 k][128 d], granule g at g^(k&15)
  u16* Vs = smem + 8192;     // [128 d][64 k], granule g at g^(d&7)
  const int tid  = threadIdx.x;
  const int wave = tid >> 6, lane = tid & 63;
  u16* Pw = smem + 16384 + wave * 1024;  // per-wave P [16 r][64 k], g^(row&7)
  const int l15  = lane & 15, quad = lane >> 4;
  const int xcd  = lin & 7, slot = lin >> 3;           // slot 0..127
  const int pairIdx = xcd * 4 + (slot & 3);            // 0..31 (b,h)
  const int b = pairIdx >> 3, h = pairIdx & 7;
  const int qtile = slot >> 2;                         // 0..31
  const long rowbase = (long)b * 2048 + qtile * 64 + wave * 16;
  const float sc = 0.08838834764831845f * 1.4426950408889634f;  // scale*log2(e)

  short8 aQ[4];
  for (int dc = 0; dc < 4; ++dc)
    aQ[dc] = *(const short8*)&qp[(rowbase + l15) * 1024 + h * 128 + dc * 32 + quad * 8];

  floatx4 O[8] = {};
  float lsum[4] = {};
  const u16* kpb   = kp + ((long)b * 512) * 1024 + h * 128;
  const u16* vbase = vT + ((long)(b * 8 + h) * 128) * 512;

  const int krow = lane >> 4;
  const int kpos = lane & 15;
  const int vrow = lane >> 3;
  const int vpos = lane & 7;

#define STAGE_K(t)                                                             \
  for (int i = 0; i < 4; ++i) {                                                \
    int inst = wave * 4 + i;                                                   \
    int row  = inst * 4 + krow;                                                \
    int g    = kpos ^ (row & 15);                                              \
    async_lds16(kpb + (long)((t) * 64 + row) * 1024 + g * 8, &Ks[inst * 512]); \
  }
#define STAGE_V(t)                                                             \
  for (int i = 0; i < 4; ++i) {                                                \
    int inst = wave * 4 + i;                                                   \
    int d    = inst * 8 + vrow;                                                \
    int g    = vpos ^ (d & 7);                                                 \
    async_lds16(vbase + (long)d * 512 + (t) * 64 + g * 8, &Vs[inst * 512]);    \
  }

  STAGE_K(0);
  STAGE_V(0);
  for (int t = 0; t < 8; ++t) {
    WAIT_VM(4);                 // K(t) landed (V(t) may still fly)
    SBAR;
    floatx4 S[4] = {};
    __builtin_amdgcn_s_setprio(1);
    for (int dc = 0; dc < 4; ++dc)
      for (int ks = 0; ks < 4; ++ks) {
        int k = ks * 16 + l15;
        short8 bk = *(const short8*)&Ks[k * 128 + (((dc * 4 + quad) ^ l15) * 8)];
        S[ks] = MFMA(aQ[dc], bk, S[ks]);
      }
    __builtin_amdgcn_s_setprio(0);
    WAIT_LGKM0;                 // Ks reads retired
    SBAR;                       // all waves done with Ks
    if (t < 7) STAGE_K(t + 1);  // flies over softmax + PV
    for (int ks = 0; ks < 4; ++ks)
      for (int r = 0; r < 4; ++r) {
        float p = fast_exp2(S[ks][r] * sc);
        lsum[r] += p;
        int row = quad * 4 + r;
        int g   = (ks * 2 + (l15 >> 3)) ^ (row & 7);
        Pw[row * 64 + g * 8 + (l15 & 7)] = f2bf(p);
      }
    short8 aP[2];
    for (int kc = 0; kc < 2; ++kc)
      aP[kc] = *(const short8*)&Pw[l15 * 64 + (((kc * 4 + quad) ^ (l15 & 7)) * 8)];
    if (t < 7) { WAIT_VM(4); }  // V(t) landed (K(t+1) may still fly)
    else       { WAIT_VM(0); }
    SBAR;
    __builtin_amdgcn_s_setprio(1);
    for (int j = 0; j < 8; ++j) {
      int d = j * 16 + l15;
      short8 bV0 = *(const short8*)&Vs[d * 64 + ((quad ^ (l15 & 7)) * 8)];
      short8 bV1 = *(const short8*)&Vs[d * 64 + (((4 + quad) ^ (l15 & 7)) * 8)];
      O[j] = MFMA(aP[0], bV0, O[j]);
      O[j] = MFMA(aP[1], bV1, O[j]);
    }
    __builtin_amdgcn_s_setprio(0);
    WAIT_LGKM0;                 // Vs reads retired
    SBAR;                       // all waves done with Vs
    if (t < 7) STAGE_V(t + 1);  // flies over QK(t+1) + softmax
  }
#undef STAGE_K
#undef STAGE_V

  for (int r = 0; r < 4; ++r) {
    float sum = lsum[r];
    for (int off = 1; off < 16; off <<= 1) sum += __shfl_xor(sum, off);
    lsum[r] = 1.f / sum;
  }
  for (int j = 0; j < 8; ++j)
    for (int r = 0; r < 4; ++r)
      ctx[(rowbase + quad * 4 + r) * 1024 + h * 128 + j * 16 + l15] =
          f2bf(O[j][r] * lsum[r]);
}

// ---------------- cooperative mega-kernel ----------------
// grid 1024 x 256, LDS 40960 B, 4 blocks/CU (all co-resident).
__global__ __launch_bounds__(256, 4)
void mega(const float* q, const float* kv, const float* Wq, const float* Wk,
          const float* Wv, const float* Wo,
          u16* q_bf, u16* kv_bf, u16* WqT, u16* WkvT, u16* WoT,
          u16* qp, u16* kp, u16* vT, u16* ctx, float* out, const float* bo) {
  __shared__ __align__(16) u16 smem[20480];   // 40960 B
  cg::grid_group g = cg::this_grid();
  const int bid = blockIdx.x;

  // P0: casts + weight transposes
  cvt_body(q, kv, q_bf, kv_bf, bid);
  transpose_body(bid, Wq, Wk, Wv, Wo, WqT, WkvT, WoT, (float*)smem);
  g.sync();

  // P2: Q-projection (bid 0..511) + fused KV-projection (bid 512..767)
  if (bid < 768) {
    const bool isQ = bid < 512;
    gemm_body(isQ ? q_bf : kv_bf, isQ ? WqT : WkvT, isQ ? qp : kp,
              nullptr, nullptr, isQ ? (u16*)nullptr : vT,
              isQ ? 1024 : 768, 1024, isQ ? bid : bid - 512, isQ ? 8 : 2, smem);
  }
  g.sync();
  // P3: attention, all 1024 blocks
  attn_body(qp, kp, vT, ctx, bid, smem);
  g.sync();
  // P4: O-projection (bid 0..511), fp32 out + bias
  if (bid < 512)
    gemm_body(ctx, WoT, nullptr, out, bo, nullptr, 1024, 1024, bid, 8, smem);
}

// ---------------- fallback standalone kernels ----------------
__global__ void cvt_all(const float* __restrict__ q, const float* __restrict__ kv,
                        u16* __restrict__ q_bf, u16* __restrict__ kv_bf) {
  int i = blockIdx.x * 256 + threadIdx.x;
  const float* src; u16* dst; int idx;
  if (i < 1048576) { src = q;  dst = q_bf;  idx = i; }
  else             { src = kv; dst = kv_bf; idx = i - 1048576; }
  float4 a = ((const float4*)src)[2 * idx];
  float4 b = ((const float4*)src)[2 * idx + 1];
  u16 t[8] = {f2bf(a.x), f2bf(a.y), f2bf(a.z), f2bf(a.w),
              f2bf(b.x), f2bf(b.y), f2bf(b.z), f2bf(b.w)};
  ((short8*)dst)[idx] = *(short8*)t;
}
__global__ __launch_bounds__(256)
void transpose_all(const float* __restrict__ Wq, const float* __restrict__ Wk,
                   const float* __restrict__ Wv, const float* __restrict__ Wo,
                   u16* __restrict__ WqT, u16* __restrict__ WkvT, u16* __restrict__ WoT) {
  __shared__ __align__(16) float tile[64 * 68];
  int bid = blockIdx.x + blockIdx.y * 16 + blockIdx.z * 256;
  transpose_body(bid, Wq, Wk, Wv, Wo, WqT, WkvT, WoT, tile);
}
__global__ __launch_bounds__(256)
void k_proj_q(const u16* __restrict__ q_bf, const u16* __restrict__ WqT,
              u16* __restrict__ qp) {
  __shared__ __align__(16) u16 smem[17664];
  gemm_body(q_bf, WqT, qp, nullptr, nullptr, nullptr, 1024, 1024, blockIdx.x, 8, smem);
}
__global__ __launch_bounds__(256)
void k_proj_kv(const u16* __restrict__ kv_bf, const u16* __restrict__ WkvT,
               u16* __restrict__ kp, u16* __restrict__ vT) {
  __shared__ __align__(16) u16 smem[17664];
  gemm_body(kv_bf, WkvT, kp, nullptr, nullptr, vT, 768, 1024, blockIdx.x, 2, smem);
}
__global__ __launch_bounds__(256, 4)
void k_attn(const u16* __restrict__ qp, const u16* __restrict__ kp,
            const u16* __restrict__ vT, u16* __restrict__ ctx) {
  __shared__ __align__(16) u16 smem[20480];
  attn_body(qp, kp, vT, ctx, blockIdx.x, smem);
}
__global__ __launch_bounds__(256)
void k_oproj(const u16* __restrict__ ctx, const u16* __restrict__ WoT,
             float* __restrict__ out, const float* __restrict__ bo) {
  __shared__ __align__(16) u16 smem[17664];
  gemm_body(ctx, WoT, nullptr, out, bo, nullptr, 1024, 1024, blockIdx.x, 8, smem);
}

extern "C" void kernel_launch(void* const* d_in, const int* in_sizes, int n_in,
                              void* d_out, int out_size, void* d_ws, size_t ws_size,
                              hipStream_t stream) {
  const float* q  = (const float*)d_in[0];
  const float* kv = (const float*)d_in[1];
  const float* Wq = (const float*)d_in[2];
  const float* Wk = (const float*)d_in[3];
  const float* Wv = (const float*)d_in[4];
  const float* Wo = (const float*)d_in[5];
  const float* bo = (const float*)d_in[6];
  float* out = (float*)d_out;

  char* ws = (char*)d_ws;
  u16* q_bf  = (u16*)(ws + 0);              // 16 MB
  u16* kv_bf = (u16*)(ws + 16777216);       //  3 MB
  u16* WqT   = (u16*)(ws + 19922944);       //  2 MB   [1024][1024]
  u16* WkvT  = (u16*)(ws + 22020096);       //  3 MB   [2048][768]
  u16* WoT   = (u16*)(ws + 25165824);       //  2 MB   [1024][1024]
  u16* qp    = (u16*)(ws + 27262976);       // 16 MB   [8192][1024]
  u16* kp    = (u16*)(ws + 44040192);       //  4 MB   [2048][1024]
  u16* vT    = (u16*)(ws + 52428800);       //  4 MB   [B][H][128][512]
  u16* ctx   = (u16*)(ws + 56623104);       // 16 MB   [8192][1024]

  // deterministic per-device decision (same every call; pure host query)
  int maxb = 0;
  hipError_t oe = hipOccupancyMaxActiveBlocksPerMultiprocessor(
      &maxb, (const void*)mega, 256, 0);
  if (oe == hipSuccess && maxb >= 4) {
    void* args[] = {(void*)&q,    (void*)&kv,    (void*)&Wq,   (void*)&Wk,
                    (void*)&Wv,   (void*)&Wo,    (void*)&q_bf, (void*)&kv_bf,
                    (void*)&WqT,  (void*)&WkvT,  (void*)&WoT,  (void*)&qp,
                    (void*)&kp,   (void*)&vT,    (void*)&ctx,  (void*)&out,
                    (void*)&bo};
    hipLaunchCooperativeKernel((const void*)mega, dim3(1024), dim3(256),
                               args, 0, stream);
  } else {
    cvt_all<<<4864, 256, 0, stream>>>(q, kv, q_bf, kv_bf);
    transpose_all<<<dim3(16, 16, 4), 256, 0, stream>>>(Wq, Wk, Wv, Wo, WqT, WkvT, WoT);
    k_proj_q<<<512, 256, 0, stream>>>(q_bf, WqT, qp);
    k_proj_kv<<<256, 256, 0, stream>>>(kv_bf, WkvT, kp, vT);
    k_attn<<<1024, 256, 0, stream>>>(qp, kp, vT, ctx);
    k_oproj<<<512, 256, 0, stream>>>(ctx, WoT, out, bo);
  }
}

// Round 5
// 182.951 us; speedup vs baseline: 1.1251x; 1.0883x over previous
//
#include <hip/hip_runtime.h>

// CrossAttention on MI355X (gfx950), bf16 MFMA path.
// B=4, Lq=2048, Lkv=512, dim_q=1024, dim_kv=768, H=8, hd=128.
// R16: R15 resubmitted verbatim (bench infra died twice; hang-audit of the
//      new 8-wave k_attn found uniform barriers, satisfiable vmcnt protocol,
//      in-bounds indexing -> infra flake suspected, need the ablation data).
//      4 plain dispatches for per-phase rocprof: k_prep (cvt+Wt),
//      k_proj_qkv (768 blk), k_attn (8 waves x qtile=128, 512x512, 48KB LDS,
//      3 blk/CU), k_oproj. GEMM bodies = R14 counted-vmcnt pipeline.

typedef unsigned short u16;
typedef unsigned int u32;
using short8  = __attribute__((ext_vector_type(8))) short;   // 8 x bf16 (4 VGPRs)
using floatx4 = __attribute__((ext_vector_type(4))) float;

__device__ inline u16 f2bf(float x) {
  union { float f; u32 u; } v; v.f = x;
  u32 r = (v.u + 0x7fffu + ((v.u >> 16) & 1u)) >> 16;  // RNE
  return (u16)r;
}

__device__ inline float fast_exp2(float x) {
#if __has_builtin(__builtin_amdgcn_exp2f)
  return __builtin_amdgcn_exp2f(x);   // v_exp_f32 (natively exp2)
#else
  return exp2f(x);
#endif
}

#define MFMA(a, b, c) __builtin_amdgcn_mfma_f32_16x16x32_bf16(a, b, c, 0, 0, 0)

__device__ inline void async_lds16(const void* g, void* l) {
  __builtin_amdgcn_global_load_lds(
      (const __attribute__((address_space(1))) void*)g,
      (__attribute__((address_space(3))) void*)l, 16, 0, 0);
}

// Counted waits + raw barrier (T4). sched_barrier(0) pins ordering (rule #18).
#define WAIT_VM(n) { asm volatile("s_waitcnt vmcnt(" #n ")" ::: "memory"); \
                     __builtin_amdgcn_sched_barrier(0); }
#define WAIT_LGKM0 { asm volatile("s_waitcnt lgkmcnt(0)" ::: "memory"); \
                     __builtin_amdgcn_sched_barrier(0); }
#define SBAR       { __builtin_amdgcn_s_barrier(); \
                     __builtin_amdgcn_sched_barrier(0); }

// ------------- W [K][N] fp32 -> Wt [N][K] bf16, one 64x64 tile per block -------
__device__ __forceinline__
void transpose_body(int bid, const float* __restrict__ Wq, const float* __restrict__ Wk,
                    const float* __restrict__ Wv, const float* __restrict__ Wo,
                    u16* __restrict__ WqT, u16* __restrict__ WkvT, u16* __restrict__ WoT,
                    float* __restrict__ tile /* [64][68] floats */) {
  const int z = bid >> 8;
  const float* W; u16* Wt; int K;
  if      (z == 0) { W = Wq; Wt = WqT;               K = 1024; }
  else if (z == 1) { W = Wk; Wt = WkvT;              K = 768;  }
  else if (z == 2) { W = Wv; Wt = WkvT + 1024 * 768; K = 768;  }
  else             { W = Wo; Wt = WoT;               K = 1024; }
  const int k0 = ((bid >> 4) & 15) * 64, n0 = (bid & 15) * 64;
  if (k0 >= K) return;  // block-uniform guard
  const int N = 1024;
  const int t = threadIdx.x;
  for (int p = 0; p < 4; ++p) {
    int cid = p * 256 + t;
    int row = cid >> 4, c = cid & 15;
    float4 v = *(const float4*)&W[(long)(k0 + row) * N + n0 + c * 4];
    tile[row * 68 + c * 4 + 0] = v.x; tile[row * 68 + c * 4 + 1] = v.y;
    tile[row * 68 + c * 4 + 2] = v.z; tile[row * 68 + c * 4 + 3] = v.w;
  }
  __syncthreads();
  for (int p = 0; p < 2; ++p) {
    int oc = p * 256 + t;
    int n = oc >> 3, c = oc & 7;
    u16 tmp[8];
    for (int s = 0; s < 8; ++s) tmp[s] = f2bf(tile[(c * 8 + s) * 68 + n]);
    *(short8*)&Wt[(long)(n0 + n) * K + k0 + c * 8] = *(short8*)tmp;
  }
}

// ---------- prep kernel: fp32->bf16 casts (bid<4864) + W transposes ----------
__global__ __launch_bounds__(256)
void k_prep(const float* __restrict__ q, const float* __restrict__ kv,
            u16* __restrict__ q_bf, u16* __restrict__ kv_bf,
            const float* __restrict__ Wq, const float* __restrict__ Wk,
            const float* __restrict__ Wv, const float* __restrict__ Wo,
            u16* __restrict__ WqT, u16* __restrict__ WkvT, u16* __restrict__ WoT) {
  __shared__ __align__(16) float tile[64 * 68];
  const int bid = blockIdx.x;
  if (bid < 4864) {
    int i = bid * 256 + threadIdx.x;   // 4864*256 == 1245184 exactly
    const float* src; u16* dst; int idx;
    if (i < 1048576) { src = q;  dst = q_bf;  idx = i; }
    else             { src = kv; dst = kv_bf; idx = i - 1048576; }
    float4 a = ((const float4*)src)[2 * idx];
    float4 b = ((const float4*)src)[2 * idx + 1];
    u16 t[8] = {f2bf(a.x), f2bf(a.y), f2bf(a.z), f2bf(a.w),
                f2bf(b.x), f2bf(b.y), f2bf(b.z), f2bf(b.w)};
    ((short8*)dst)[idx] = *(short8*)t;
  } else {
    transpose_body(bid - 4864, Wq, Wk, Wv, Wo, WqT, WkvT, WoT, tile);
  }
}

// ------- bf16 GEMM body: BK=32 dbuf, counted-vmcnt pipeline (T3+T4) -------
__device__ __forceinline__
void gemm_body(const u16* __restrict__ A, const u16* __restrict__ Bt,
               u16* __restrict__ Cb, float* __restrict__ Cf,
               const float* __restrict__ bias, u16* __restrict__ vt_out,
               int K, int ldc, int lin, int mt_per_xcd, u16* smem) {
  const int tid  = threadIdx.x;
  const int wave = tid >> 6, lane = tid & 63;
  const int l15  = lane & 15, quad = lane >> 4;
  const int wm   = (wave >> 1) * 64, wn = (wave & 1) * 64;
  const int xcd  = lin & 7, slot = lin >> 3;
  const int mt   = xcd * mt_per_xcd + (slot % mt_per_xcd);
  const int nti  = slot / mt_per_xcd;
  const long m0  = (long)mt * 128, n0 = (long)nti * 128;

  // T2 pair-row layout: LDS buf = [64 pair-rows][64 u16]; pair-row p packs
  // rows {2p,2p+1} x 32 k. Granule g=(r&1)*4+k/8 stored at g^(p&7); involution
  // applied at the SOURCE addr (rule #21), LDS dest linear.
  const int pl  = lane >> 3;
  const int gg  = (lane & 7) ^ pl;
  const int ro  = pl * 2 + (gg >> 2);
  const int co  = (gg & 3) * 8;
  const u16* Aw = A  + (m0 + wave * 32 + ro) * (long)K + co;
  const u16* Bw = Bt + (n0 + wave * 32 + ro) * (long)K + co;
  u16* const A0 = smem;        u16* const B0 = smem + 4096;
  u16* const A1 = smem + 8192; u16* const B1 = smem + 12288;
  const int rdo  = ((((l15 & 1) << 2) | quad) ^ (l15 >> 1)) * 8;
  const int aoff = wm * 32 + (l15 >> 1) * 64 + rdo;
  const int boff = wn * 32 + (l15 >> 1) * 64 + rdo;

#define STAGE_G(Ab, Bb, kk)                                          \
  { async_lds16(Aw + (kk),                (Ab) + wave * 1024);       \
    async_lds16(Aw + 16 * (long)K + (kk), (Ab) + wave * 1024 + 512); \
    async_lds16(Bw + (kk),                (Bb) + wave * 1024);       \
    async_lds16(Bw + 16 * (long)K + (kk), (Bb) + wave * 1024 + 512); }

  floatx4 acc[4][4] = {};
  STAGE_G(A0, B0, 0);
  const int NS = K >> 5;
  for (int s = 0; s < NS; ++s) {
    u16* Ac = (s & 1) ? A1 : A0; u16* Bc = (s & 1) ? B1 : B0;
    if (s + 1 < NS) {           // issue next stage FIRST; it flies over compute
      u16* An = (s & 1) ? A0 : A1; u16* Bn = (s & 1) ? B0 : B1;
      STAGE_G(An, Bn, (s + 1) * 32);
      WAIT_VM(4);               // stage(s) landed; stage(s+1) stays in flight
    } else {
      WAIT_VM(0);
    }
    SBAR;
    short8 af[4], bfr[4];
    for (int i = 0; i < 4; ++i) af[i]  = *(const short8*)&Ac[aoff + i * 512];
    for (int j = 0; j < 4; ++j) bfr[j] = *(const short8*)&Bc[boff + j * 512];
    for (int i = 0; i < 4; ++i)
      for (int j = 0; j < 4; ++j)
        acc[i][j] = MFMA(af[i], bfr[j], acc[i][j]);
    WAIT_LGKM0;
    SBAR;
  }
#undef STAGE_G

  if (Cf) {
    for (int i = 0; i < 4; ++i)
      for (int j = 0; j < 4; ++j) {
        long row = m0 + wm + i * 16 + quad * 4;
        long col = n0 + wn + j * 16 + l15;
        float b = bias ? bias[col] : 0.f;
        for (int r = 0; r < 4; ++r) Cf[(row + r) * (long)ldc + col] = acc[i][j][r] + b;
      }
    return;
  }
  for (int i = 0; i < 4; ++i)
    for (int j = 0; j < 4; ++j)
      for (int r = 0; r < 4; ++r)
        smem[(wm + i * 16 + quad * 4 + r) * 138 + wn + j * 16 + l15] = f2bf(acc[i][j][r]);
  __syncthreads();
  if (vt_out && nti >= 8) {
    const int h  = nti - 8;
    const int bq = (int)(m0 >> 9);
    const int l0 = (int)(m0 & 511);
    u16* vbase = vt_out + ((long)(bq * 8 + h) * 128) * 512;
    for (int p = 0; p < 8; ++p) {
      int cid = p * 256 + tid;
      int d = cid >> 4, c = cid & 15;
      u16 tmp[8];
      for (int s = 0; s < 8; ++s) tmp[s] = smem[(c * 8 + s) * 138 + d];
      *(short8*)&vbase[(long)d * 512 + l0 + c * 8] = *(short8*)tmp;
    }
  } else {
    for (int p = 0; p < 8; ++p) {
      int cid = p * 256 + tid;
      int row = cid >> 4, c = cid & 15;
      short8 v = *(const short8*)&smem[row * 138 + c * 8];
      *(short8*)&Cb[(m0 + row) * (long)ldc + n0 + c * 8] = v;
    }
  }
}

// ---- fused Q+KV projection: 768 blocks (0..511 Q, 512..767 KV) ----
__global__ __launch_bounds__(256)
void k_proj_qkv(const u16* __restrict__ q_bf, const u16* __restrict__ WqT,
                const u16* __restrict__ kv_bf, const u16* __restrict__ WkvT,
                u16* __restrict__ qp, u16* __restrict__ kp, u16* __restrict__ vT) {
  __shared__ __align__(16) u16 smem[17664];
  const int bid = blockIdx.x;
  if (bid < 512)
    gemm_body(q_bf, WqT, qp, nullptr, nullptr, nullptr, 1024, 1024, bid, 8, smem);
  else
    gemm_body(kv_bf, WkvT, kp, nullptr, nullptr, vT, 768, 1024, bid - 512, 2, smem);
}

// ------- flash attention: 8 waves x qtile=128, counted-vmcnt K/V staging -------
// 512 blocks x 512 threads. LDS: Ks 16KB + Vs 16KB + P 8x2KB = 48KB (3 blk/CU,
// 24 waves/CU). Per-wave math identical to R12-verified 4-wave version; only
// staging split (2 insts/wave) and indexing differ.
__global__ __launch_bounds__(512)
void k_attn(const u16* __restrict__ qp, const u16* __restrict__ kp,
            const u16* __restrict__ vT, u16* __restrict__ ctx) {
  __shared__ __align__(16) u16 smem[24576];   // 49152 B
  u16* Ks = smem;            // [64 k][128 d], granule g at g^(k&15)
  u16* Vs = smem + 8192;     // [128 d][64 k], granule g at g^(d&7)
  const int lin  = blockIdx.x;                 // 0..511
  const int tid  = threadIdx.x;
  const int wave = tid >> 6, lane = tid & 63;  // wave 0..7
  u16* Pw = smem + 16384 + wave * 1024;        // per-wave P [16 r][64 k], g^(row&7)
  const int l15  = lane & 15, quad = lane >> 4;
  const int xcd  = lin & 7, slot = lin >> 3;   // slot 0..63
  const int pairIdx = xcd * 4 + (slot & 3);    // 0..31 (b,h)
  const int b = pairIdx >> 3, h = pairIdx & 7;
  const int qtile = slot >> 2;                 // 0..15
  const long rowbase = (long)b * 2048 + qtile * 128 + wave * 16;
  const float sc = 0.08838834764831845f * 1.4426950408889634f;  // scale*log2(e)

  short8 aQ[4];
  for (int dc = 0; dc < 4; ++dc)
    aQ[dc] = *(const short8*)&qp[(rowbase + l15) * 1024 + h * 128 + dc * 32 + quad * 8];

  floatx4 O[8] = {};
  float lsum[4] = {};
  const u16* kpb   = kp + ((long)b * 512) * 1024 + h * 128;
  const u16* vbase = vT + ((long)(b * 8 + h) * 128) * 512;

  const int krow = lane >> 4;
  const int kpos = lane & 15;
  const int vrow = lane >> 3;
  const int vpos = lane & 7;

  // 8 waves: each stages 2 of 16 insts for K (4 rows/inst) and V (8 d/inst).
#define STAGE_K(t)                                                             \
  for (int i = 0; i < 2; ++i) {                                                \
    int inst = wave * 2 + i;                                                   \
    int row  = inst * 4 + krow;                                                \
    int g    = kpos ^ (row & 15);                                              \
    async_lds16(kpb + (long)((t) * 64 + row) * 1024 + g * 8, &Ks[inst * 512]); \
  }
#define STAGE_V(t)                                                             \
  for (int i = 0; i < 2; ++i) {                                                \
    int inst = wave * 2 + i;                                                   \
    int d    = inst * 8 + vrow;                                                \
    int g    = vpos ^ (d & 7);                                                 \
    async_lds16(vbase + (long)d * 512 + (t) * 64 + g * 8, &Vs[inst * 512]);    \
  }

  STAGE_K(0);
  STAGE_V(0);
  for (int t = 0; t < 8; ++t) {
    WAIT_VM(2);                 // K(t) landed (V(t) may still fly)
    SBAR;
    floatx4 S[4] = {};
    __builtin_amdgcn_s_setprio(1);
    for (int dc = 0; dc < 4; ++dc)
      for (int ks = 0; ks < 4; ++ks) {
        int k = ks * 16 + l15;
        short8 bk = *(const short8*)&Ks[k * 128 + (((dc * 4 + quad) ^ l15) * 8)];
        S[ks] = MFMA(aQ[dc], bk, S[ks]);
      }
    __builtin_amdgcn_s_setprio(0);
    WAIT_LGKM0;                 // Ks reads retired
    SBAR;                       // all waves done with Ks
    if (t < 7) STAGE_K(t + 1);  // flies over softmax + PV
    for (int ks = 0; ks < 4; ++ks)
      for (int r = 0; r < 4; ++r) {
        float p = fast_exp2(S[ks][r] * sc);
        lsum[r] += p;
        int row = quad * 4 + r;
        int g   = (ks * 2 + (l15 >> 3)) ^ (row & 7);
        Pw[row * 64 + g * 8 + (l15 & 7)] = f2bf(p);
      }
    short8 aP[2];
    for (int kc = 0; kc < 2; ++kc)
      aP[kc] = *(const short8*)&Pw[l15 * 64 + (((kc * 4 + quad) ^ (l15 & 7)) * 8)];
    if (t < 7) { WAIT_VM(2); }  // V(t) landed (K(t+1) may still fly)
    else       { WAIT_VM(0); }
    SBAR;
    __builtin_amdgcn_s_setprio(1);
    for (int j = 0; j < 8; ++j) {
      int d = j * 16 + l15;
      short8 bV0 = *(const short8*)&Vs[d * 64 + ((quad ^ (l15 & 7)) * 8)];
      short8 bV1 = *(const short8*)&Vs[d * 64 + (((4 + quad) ^ (l15 & 7)) * 8)];
      O[j] = MFMA(aP[0], bV0, O[j]);
      O[j] = MFMA(aP[1], bV1, O[j]);
    }
    __builtin_amdgcn_s_setprio(0);
    WAIT_LGKM0;                 // Vs reads retired
    SBAR;                       // all waves done with Vs
    if (t < 7) STAGE_V(t + 1);  // flies over QK(t+1) + softmax
  }
#undef STAGE_K
#undef STAGE_V

  for (int r = 0; r < 4; ++r) {
    float sum = lsum[r];
    for (int off = 1; off < 16; off <<= 1) sum += __shfl_xor(sum, off);
    lsum[r] = 1.f / sum;
  }
  for (int j = 0; j < 8; ++j)
    for (int r = 0; r < 4; ++r)
      ctx[(rowbase + quad * 4 + r) * 1024 + h * 128 + j * 16 + l15] =
          f2bf(O[j][r] * lsum[r]);
}

// ---------------- O-projection ----------------
__global__ __launch_bounds__(256)
void k_oproj(const u16* __restrict__ ctx, const u16* __restrict__ WoT,
             float* __restrict__ out, const float* __restrict__ bo) {
  __shared__ __align__(16) u16 smem[17664];
  gemm_body(ctx, WoT, nullptr, out, bo, nullptr, 1024, 1024, blockIdx.x, 8, smem);
}

extern "C" void kernel_launch(void* const* d_in, const int* in_sizes, int n_in,
                              void* d_out, int out_size, void* d_ws, size_t ws_size,
                              hipStream_t stream) {
  const float* q  = (const float*)d_in[0];
  const float* kv = (const float*)d_in[1];
  const float* Wq = (const float*)d_in[2];
  const float* Wk = (const float*)d_in[3];
  const float* Wv = (const float*)d_in[4];
  const float* Wo = (const float*)d_in[5];
  const float* bo = (const float*)d_in[6];
  float* out = (float*)d_out;

  char* ws = (char*)d_ws;
  u16* q_bf  = (u16*)(ws + 0);              // 16 MB
  u16* kv_bf = (u16*)(ws + 16777216);       //  3 MB
  u16* WqT   = (u16*)(ws + 19922944);       //  2 MB   [1024][1024]
  u16* WkvT  = (u16*)(ws + 22020096);       //  3 MB   [2048][768]
  u16* WoT   = (u16*)(ws + 25165824);       //  2 MB   [1024][1024]
  u16* qp    = (u16*)(ws + 27262976);       // 16 MB   [8192][1024]
  u16* kp    = (u16*)(ws + 44040192);       //  4 MB   [2048][1024]
  u16* vT    = (u16*)(ws + 52428800);       //  4 MB   [B][H][128][512]
  u16* ctx   = (u16*)(ws + 56623104);       // 16 MB   [8192][1024]

  k_prep<<<5888, 256, 0, stream>>>(q, kv, q_bf, kv_bf, Wq, Wk, Wv, Wo,
                                   WqT, WkvT, WoT);
  k_proj_qkv<<<768, 256, 0, stream>>>(q_bf, WqT, kv_bf, WkvT, qp, kp, vT);
  k_attn<<<512, 512, 0, stream>>>(qp, kp, vT, ctx);
  k_oproj<<<512, 256, 0, stream>>>(ctx, WoT, out, bo);
}

// Round 6
// 181.679 us; speedup vs baseline: 1.1330x; 1.0070x over previous
//
#include <hip/hip_runtime.h>

// CrossAttention on MI355X (gfx950), bf16 MFMA path.
// B=4, Lq=2048, Lkv=512, dim_q=1024, dim_kv=768, H=8, hd=128.
// R17: gemm_body 2-deep -> 3-deep pipeline (BK=32 TRIPLE buffer, 48KB LDS,
//      stage s+2 issued at top of iter s, WAIT_VM(8) steady state). Evidence:
//      R16 GEMM phases ~550 TF; per-step stall = HBM latency (~600-900cy,
//      m126) minus 1-step issue distance (~350cy) -> ~40-50% stall at the
//      vmcnt wait. Depth 3 gives ~700cy in flight. T4 formula: N = 4 loads x
//      2 stages = vmcnt(8). Attn/prep unchanged (R16-proven, attn < 40us).

typedef unsigned short u16;
typedef unsigned int u32;
using short8  = __attribute__((ext_vector_type(8))) short;   // 8 x bf16 (4 VGPRs)
using floatx4 = __attribute__((ext_vector_type(4))) float;

__device__ inline u16 f2bf(float x) {
  union { float f; u32 u; } v; v.f = x;
  u32 r = (v.u + 0x7fffu + ((v.u >> 16) & 1u)) >> 16;  // RNE
  return (u16)r;
}

__device__ inline float fast_exp2(float x) {
#if __has_builtin(__builtin_amdgcn_exp2f)
  return __builtin_amdgcn_exp2f(x);   // v_exp_f32 (natively exp2)
#else
  return exp2f(x);
#endif
}

#define MFMA(a, b, c) __builtin_amdgcn_mfma_f32_16x16x32_bf16(a, b, c, 0, 0, 0)

__device__ inline void async_lds16(const void* g, void* l) {
  __builtin_amdgcn_global_load_lds(
      (const __attribute__((address_space(1))) void*)g,
      (__attribute__((address_space(3))) void*)l, 16, 0, 0);
}

// Counted waits + raw barrier (T4). sched_barrier(0) pins ordering (rule #18).
#define WAIT_VM(n) { asm volatile("s_waitcnt vmcnt(" #n ")" ::: "memory"); \
                     __builtin_amdgcn_sched_barrier(0); }
#define WAIT_LGKM0 { asm volatile("s_waitcnt lgkmcnt(0)" ::: "memory"); \
                     __builtin_amdgcn_sched_barrier(0); }
#define SBAR       { __builtin_amdgcn_s_barrier(); \
                     __builtin_amdgcn_sched_barrier(0); }

// ------------- W [K][N] fp32 -> Wt [N][K] bf16, one 64x64 tile per block -------
__device__ __forceinline__
void transpose_body(int bid, const float* __restrict__ Wq, const float* __restrict__ Wk,
                    const float* __restrict__ Wv, const float* __restrict__ Wo,
                    u16* __restrict__ WqT, u16* __restrict__ WkvT, u16* __restrict__ WoT,
                    float* __restrict__ tile /* [64][68] floats */) {
  const int z = bid >> 8;
  const float* W; u16* Wt; int K;
  if      (z == 0) { W = Wq; Wt = WqT;               K = 1024; }
  else if (z == 1) { W = Wk; Wt = WkvT;              K = 768;  }
  else if (z == 2) { W = Wv; Wt = WkvT + 1024 * 768; K = 768;  }
  else             { W = Wo; Wt = WoT;               K = 1024; }
  const int k0 = ((bid >> 4) & 15) * 64, n0 = (bid & 15) * 64;
  if (k0 >= K) return;  // block-uniform guard
  const int N = 1024;
  const int t = threadIdx.x;
  for (int p = 0; p < 4; ++p) {
    int cid = p * 256 + t;
    int row = cid >> 4, c = cid & 15;
    float4 v = *(const float4*)&W[(long)(k0 + row) * N + n0 + c * 4];
    tile[row * 68 + c * 4 + 0] = v.x; tile[row * 68 + c * 4 + 1] = v.y;
    tile[row * 68 + c * 4 + 2] = v.z; tile[row * 68 + c * 4 + 3] = v.w;
  }
  __syncthreads();
  for (int p = 0; p < 2; ++p) {
    int oc = p * 256 + t;
    int n = oc >> 3, c = oc & 7;
    u16 tmp[8];
    for (int s = 0; s < 8; ++s) tmp[s] = f2bf(tile[(c * 8 + s) * 68 + n]);
    *(short8*)&Wt[(long)(n0 + n) * K + k0 + c * 8] = *(short8*)tmp;
  }
}

// ---------- prep kernel: fp32->bf16 casts (bid<4864) + W transposes ----------
__global__ __launch_bounds__(256)
void k_prep(const float* __restrict__ q, const float* __restrict__ kv,
            u16* __restrict__ q_bf, u16* __restrict__ kv_bf,
            const float* __restrict__ Wq, const float* __restrict__ Wk,
            const float* __restrict__ Wv, const float* __restrict__ Wo,
            u16* __restrict__ WqT, u16* __restrict__ WkvT, u16* __restrict__ WoT) {
  __shared__ __align__(16) float tile[64 * 68];
  const int bid = blockIdx.x;
  if (bid < 4864) {
    int i = bid * 256 + threadIdx.x;   // 4864*256 == 1245184 exactly
    const float* src; u16* dst; int idx;
    if (i < 1048576) { src = q;  dst = q_bf;  idx = i; }
    else             { src = kv; dst = kv_bf; idx = i - 1048576; }
    float4 a = ((const float4*)src)[2 * idx];
    float4 b = ((const float4*)src)[2 * idx + 1];
    u16 t[8] = {f2bf(a.x), f2bf(a.y), f2bf(a.z), f2bf(a.w),
                f2bf(b.x), f2bf(b.y), f2bf(b.z), f2bf(b.w)};
    ((short8*)dst)[idx] = *(short8*)t;
  } else {
    transpose_body(bid - 4864, Wq, Wk, Wv, Wo, WqT, WkvT, WoT, tile);
  }
}

// ------- bf16 GEMM body: BK=32 TRIPLE buffer, 3-deep counted-vmcnt pipeline -------
// smem must be >= 24576 u16 (48 KB): buf k at smem + k*8192 (A 4096 | B 4096).
__device__ __forceinline__
void gemm_body(const u16* __restrict__ A, const u16* __restrict__ Bt,
               u16* __restrict__ Cb, float* __restrict__ Cf,
               const float* __restrict__ bias, u16* __restrict__ vt_out,
               int K, int ldc, int lin, int mt_per_xcd, u16* smem) {
  const int tid  = threadIdx.x;
  const int wave = tid >> 6, lane = tid & 63;
  const int l15  = lane & 15, quad = lane >> 4;
  const int wm   = (wave >> 1) * 64, wn = (wave & 1) * 64;
  const int xcd  = lin & 7, slot = lin >> 3;
  const int mt   = xcd * mt_per_xcd + (slot % mt_per_xcd);
  const int nti  = slot / mt_per_xcd;
  const long m0  = (long)mt * 128, n0 = (long)nti * 128;

  // T2 pair-row layout: LDS buf = [64 pair-rows][64 u16]; pair-row p packs
  // rows {2p,2p+1} x 32 k. Granule g=(r&1)*4+k/8 stored at g^(p&7); involution
  // applied at the SOURCE addr (rule #21), LDS dest linear.
  const int pl  = lane >> 3;
  const int gg  = (lane & 7) ^ pl;
  const int ro  = pl * 2 + (gg >> 2);
  const int co  = (gg & 3) * 8;
  const u16* Aw = A  + (m0 + wave * 32 + ro) * (long)K + co;
  const u16* Bw = Bt + (n0 + wave * 32 + ro) * (long)K + co;
  const int rdo  = ((((l15 & 1) << 2) | quad) ^ (l15 >> 1)) * 8;
  const int aoff = wm * 32 + (l15 >> 1) * 64 + rdo;
  const int boff = wn * 32 + (l15 >> 1) * 64 + rdo;

  // stage into buffer base Bse (u16*): A at Bse, B at Bse+4096
#define STAGE_G(Bse, kk)                                                   \
  { u16* Ab_ = (Bse); u16* Bb_ = (Bse) + 4096;                             \
    async_lds16(Aw + (kk),                Ab_ + wave * 1024);              \
    async_lds16(Aw + 16 * (long)K + (kk), Ab_ + wave * 1024 + 512);        \
    async_lds16(Bw + (kk),                Bb_ + wave * 1024);              \
    async_lds16(Bw + 16 * (long)K + (kk), Bb_ + wave * 1024 + 512); }

  floatx4 acc[4][4] = {};
  const int NS = K >> 5;                 // 24 or 32 here (>= 3)
  STAGE_G(smem, 0);                      // stage 0 -> buf 0
  STAGE_G(smem + 8192, 32);              // stage 1 -> buf 1
  int cb = 0, nb = 2;                    // compute buf, next-stage buf
  for (int s = 0; s < NS; ++s) {
    u16* Ac = smem + cb * 8192; u16* Bc = Ac + 4096;
    if (s + 2 < NS) {                    // issue stage s+2 (buf nb is free:
      STAGE_G(smem + nb * 8192, (s + 2) * 32);   // its reads ended at s-1)
      WAIT_VM(8);                        // stage(s) landed; s+1, s+2 in flight
    } else if (s + 1 < NS) {
      WAIT_VM(4);                        // stage(s) landed; s+1 in flight
    } else {
      WAIT_VM(0);
    }
    SBAR;                                // all waves' stage(s) landed
    short8 af[4], bfr[4];
    for (int i = 0; i < 4; ++i) af[i]  = *(const short8*)&Ac[aoff + i * 512];
    for (int j = 0; j < 4; ++j) bfr[j] = *(const short8*)&Bc[boff + j * 512];
    for (int i = 0; i < 4; ++i)
      for (int j = 0; j < 4; ++j)
        acc[i][j] = MFMA(af[i], bfr[j], acc[i][j]);
    WAIT_LGKM0;                          // this wave's reads of buf cb retired
    SBAR;                                // everyone done with buf cb
    cb = (cb == 2) ? 0 : cb + 1;
    nb = (nb == 2) ? 0 : nb + 1;
  }
#undef STAGE_G

  if (Cf) {
    for (int i = 0; i < 4; ++i)
      for (int j = 0; j < 4; ++j) {
        long row = m0 + wm + i * 16 + quad * 4;
        long col = n0 + wn + j * 16 + l15;
        float b = bias ? bias[col] : 0.f;
        for (int r = 0; r < 4; ++r) Cf[(row + r) * (long)ldc + col] = acc[i][j][r] + b;
      }
    return;
  }
  for (int i = 0; i < 4; ++i)
    for (int j = 0; j < 4; ++j)
      for (int r = 0; r < 4; ++r)
        smem[(wm + i * 16 + quad * 4 + r) * 138 + wn + j * 16 + l15] = f2bf(acc[i][j][r]);
  __syncthreads();
  if (vt_out && nti >= 8) {
    const int h  = nti - 8;
    const int bq = (int)(m0 >> 9);
    const int l0 = (int)(m0 & 511);
    u16* vbase = vt_out + ((long)(bq * 8 + h) * 128) * 512;
    for (int p = 0; p < 8; ++p) {
      int cid = p * 256 + tid;
      int d = cid >> 4, c = cid & 15;
      u16 tmp[8];
      for (int s = 0; s < 8; ++s) tmp[s] = smem[(c * 8 + s) * 138 + d];
      *(short8*)&vbase[(long)d * 512 + l0 + c * 8] = *(short8*)tmp;
    }
  } else {
    for (int p = 0; p < 8; ++p) {
      int cid = p * 256 + tid;
      int row = cid >> 4, c = cid & 15;
      short8 v = *(const short8*)&smem[row * 138 + c * 8];
      *(short8*)&Cb[(m0 + row) * (long)ldc + n0 + c * 8] = v;
    }
  }
}

// ---- fused Q+KV projection: 768 blocks (0..511 Q, 512..767 KV) ----
__global__ __launch_bounds__(256)
void k_proj_qkv(const u16* __restrict__ q_bf, const u16* __restrict__ WqT,
                const u16* __restrict__ kv_bf, const u16* __restrict__ WkvT,
                u16* __restrict__ qp, u16* __restrict__ kp, u16* __restrict__ vT) {
  __shared__ __align__(16) u16 smem[24576];   // 48 KB: 3-buf (epi aliases)
  const int bid = blockIdx.x;
  if (bid < 512)
    gemm_body(q_bf, WqT, qp, nullptr, nullptr, nullptr, 1024, 1024, bid, 8, smem);
  else
    gemm_body(kv_bf, WkvT, kp, nullptr, nullptr, vT, 768, 1024, bid - 512, 2, smem);
}

// ------- flash attention: 8 waves x qtile=128, counted-vmcnt K/V staging -------
// 512 blocks x 512 threads. LDS: Ks 16KB + Vs 16KB + P 8x2KB = 48KB.
__global__ __launch_bounds__(512)
void k_attn(const u16* __restrict__ qp, const u16* __restrict__ kp,
            const u16* __restrict__ vT, u16* __restrict__ ctx) {
  __shared__ __align__(16) u16 smem[24576];   // 49152 B
  u16* Ks = smem;            // [64 k][128 d], granule g at g^(k&15)
  u16* Vs = smem + 8192;     // [128 d][64 k], granule g at g^(d&7)
  const int lin  = blockIdx.x;                 // 0..511
  const int tid  = threadIdx.x;
  const int wave = tid >> 6, lane = tid & 63;  // wave 0..7
  u16* Pw = smem + 16384 + wave * 1024;        // per-wave P [16 r][64 k], g^(row&7)
  const int l15  = lane & 15, quad = lane >> 4;
  const int xcd  = lin & 7, slot = lin >> 3;   // slot 0..63
  const int pairIdx = xcd * 4 + (slot & 3);    // 0..31 (b,h)
  const int b = pairIdx >> 3, h = pairIdx & 7;
  const int qtile = slot >> 2;                 // 0..15
  const long rowbase = (long)b * 2048 + qtile * 128 + wave * 16;
  const float sc = 0.08838834764831845f * 1.4426950408889634f;  // scale*log2(e)

  short8 aQ[4];
  for (int dc = 0; dc < 4; ++dc)
    aQ[dc] = *(const short8*)&qp[(rowbase + l15) * 1024 + h * 128 + dc * 32 + quad * 8];

  floatx4 O[8] = {};
  float lsum[4] = {};
  const u16* kpb   = kp + ((long)b * 512) * 1024 + h * 128;
  const u16* vbase = vT + ((long)(b * 8 + h) * 128) * 512;

  const int krow = lane >> 4;
  const int kpos = lane & 15;
  const int vrow = lane >> 3;
  const int vpos = lane & 7;

  // 8 waves: each stages 2 of 16 insts for K (4 rows/inst) and V (8 d/inst).
#define STAGE_K(t)                                                             \
  for (int i = 0; i < 2; ++i) {                                                \
    int inst = wave * 2 + i;                                                   \
    int row  = inst * 4 + krow;                                                \
    int g    = kpos ^ (row & 15);                                              \
    async_lds16(kpb + (long)((t) * 64 + row) * 1024 + g * 8, &Ks[inst * 512]); \
  }
#define STAGE_V(t)                                                             \
  for (int i = 0; i < 2; ++i) {                                                \
    int inst = wave * 2 + i;                                                   \
    int d    = inst * 8 + vrow;                                                \
    int g    = vpos ^ (d & 7);                                                 \
    async_lds16(vbase + (long)d * 512 + (t) * 64 + g * 8, &Vs[inst * 512]);    \
  }

  STAGE_K(0);
  STAGE_V(0);
  for (int t = 0; t < 8; ++t) {
    WAIT_VM(2);                 // K(t) landed (V(t) may still fly)
    SBAR;
    floatx4 S[4] = {};
    __builtin_amdgcn_s_setprio(1);
    for (int dc = 0; dc < 4; ++dc)
      for (int ks = 0; ks < 4; ++ks) {
        int k = ks * 16 + l15;
        short8 bk = *(const short8*)&Ks[k * 128 + (((dc * 4 + quad) ^ l15) * 8)];
        S[ks] = MFMA(aQ[dc], bk, S[ks]);
      }
    __builtin_amdgcn_s_setprio(0);
    WAIT_LGKM0;                 // Ks reads retired
    SBAR;                       // all waves done with Ks
    if (t < 7) STAGE_K(t + 1);  // flies over softmax + PV
    for (int ks = 0; ks < 4; ++ks)
      for (int r = 0; r < 4; ++r) {
        float p = fast_exp2(S[ks][r] * sc);
        lsum[r] += p;
        int row = quad * 4 + r;
        int g   = (ks * 2 + (l15 >> 3)) ^ (row & 7);
        Pw[row * 64 + g * 8 + (l15 & 7)] = f2bf(p);
      }
    short8 aP[2];
    for (int kc = 0; kc < 2; ++kc)
      aP[kc] = *(const short8*)&Pw[l15 * 64 + (((kc * 4 + quad) ^ (l15 & 7)) * 8)];
    if (t < 7) { WAIT_VM(2); }  // V(t) landed (K(t+1) may still fly)
    else       { WAIT_VM(0); }
    SBAR;
    __builtin_amdgcn_s_setprio(1);
    for (int j = 0; j < 8; ++j) {
      int d = j * 16 + l15;
      short8 bV0 = *(const short8*)&Vs[d * 64 + ((quad ^ (l15 & 7)) * 8)];
      short8 bV1 = *(const short8*)&Vs[d * 64 + (((4 + quad) ^ (l15 & 7)) * 8)];
      O[j] = MFMA(aP[0], bV0, O[j]);
      O[j] = MFMA(aP[1], bV1, O[j]);
    }
    __builtin_amdgcn_s_setprio(0);
    WAIT_LGKM0;                 // Vs reads retired
    SBAR;                       // all waves done with Vs
    if (t < 7) STAGE_V(t + 1);  // flies over QK(t+1) + softmax
  }
#undef STAGE_K
#undef STAGE_V

  for (int r = 0; r < 4; ++r) {
    float sum = lsum[r];
    for (int off = 1; off < 16; off <<= 1) sum += __shfl_xor(sum, off);
    lsum[r] = 1.f / sum;
  }
  for (int j = 0; j < 8; ++j)
    for (int r = 0; r < 4; ++r)
      ctx[(rowbase + quad * 4 + r) * 1024 + h * 128 + j * 16 + l15] =
          f2bf(O[j][r] * lsum[r]);
}

// ---------------- O-projection ----------------
__global__ __launch_bounds__(256)
void k_oproj(const u16* __restrict__ ctx, const u16* __restrict__ WoT,
             float* __restrict__ out, const float* __restrict__ bo) {
  __shared__ __align__(16) u16 smem[24576];   // 48 KB: 3-buf
  gemm_body(ctx, WoT, nullptr, out, bo, nullptr, 1024, 1024, blockIdx.x, 8, smem);
}

extern "C" void kernel_launch(void* const* d_in, const int* in_sizes, int n_in,
                              void* d_out, int out_size, void* d_ws, size_t ws_size,
                              hipStream_t stream) {
  const float* q  = (const float*)d_in[0];
  const float* kv = (const float*)d_in[1];
  const float* Wq = (const float*)d_in[2];
  const float* Wk = (const float*)d_in[3];
  const float* Wv = (const float*)d_in[4];
  const float* Wo = (const float*)d_in[5];
  const float* bo = (const float*)d_in[6];
  float* out = (float*)d_out;

  char* ws = (char*)d_ws;
  u16* q_bf  = (u16*)(ws + 0);              // 16 MB
  u16* kv_bf = (u16*)(ws + 16777216);       //  3 MB
  u16* WqT   = (u16*)(ws + 19922944);       //  2 MB   [1024][1024]
  u16* WkvT  = (u16*)(ws + 22020096);       //  3 MB   [2048][768]
  u16* WoT   = (u16*)(ws + 25165824);       //  2 MB   [1024][1024]
  u16* qp    = (u16*)(ws + 27262976);       // 16 MB   [8192][1024]
  u16* kp    = (u16*)(ws + 44040192);       //  4 MB   [2048][1024]
  u16* vT    = (u16*)(ws + 52428800);       //  4 MB   [B][H][128][512]
  u16* ctx   = (u16*)(ws + 56623104);       // 16 MB   [8192][1024]

  k_prep<<<5888, 256, 0, stream>>>(q, kv, q_bf, kv_bf, Wq, Wk, Wv, Wo,
                                   WqT, WkvT, WoT);
  k_proj_qkv<<<768, 256, 0, stream>>>(q_bf, WqT, kv_bf, WkvT, qp, kp, vT);
  k_attn<<<512, 512, 0, stream>>>(qp, kp, vT, ctx);
  k_oproj<<<512, 256, 0, stream>>>(ctx, WoT, out, bo);
}